// Round 2
// baseline (254.876 us; speedup 1.0000x reference)
//
#include <hip/hip_runtime.h>
#include <hip/hip_bf16.h>

// USR_EMB: out[b,h,:] = emb_usr[searchsorted(userlist, x[b,h]), :]
// EMB = 64 floats = 16 float4 = 256 B per row.
//
// Phase 1 (per lane): interpolation probe — userlist is strictly increasing
//   and (in this dataset) a dense range, so guess = 1 + (u - userlist[1])
//   verifies in ONE load. Binary-search fallback keeps it correct for any
//   sorted unique userlist.
// Phase 2 (per wave, no LDS / no barrier): wave owns 64 elements; ids are
//   exchanged via __shfl. Lane layout: 16 lanes per row -> each wave-store
//   is 4 rows x 256 B = 1 KB contiguous; gathers are full 256 B segments.
//
// R6: nt (non-temporal) output stores, take 2. R5 failed to COMPILE: HIP's
//   float4 is a struct, which asm "v" constraints can't register-map
//   ("indirect register inputs"). Fix: use a native ext_vector_type(4)
//   float for the row value — that maps to a VGPR quad — and pass the
//   address as a plain pointer (VGPR pair). Rationale unchanged: the
//   209.7 MB write-once output stream evicts the 25.6 MB emb table from
//   L2/L3; `nt` keeps the table cache-resident for the random gathers.

#define V4_PER_ROW 16  // 64 floats / 4

typedef float f32x4 __attribute__((ext_vector_type(4)));

__device__ __forceinline__ void store_nt_f4(f32x4* p, f32x4 v)
{
    // %0 = address (VGPR pair), %1 = data (VGPR quad). Executes under the
    // current exec mask, so the guarded-branch predication still applies.
    asm volatile("global_store_dwordx4 %0, %1, off nt"
                 :
                 : "v"(p), "v"(v)
                 : "memory");
}

__global__ __launch_bounds__(256) void usr_emb_gather(
    const int* __restrict__ x,
    const int* __restrict__ userlist, int n_user,
    const float* __restrict__ emb,
    float* __restrict__ out,
    int n_elem)
{
    const int t      = threadIdx.x;
    const int lane   = t & 63;
    const int wave   = t >> 6;
    const int wbase  = blockIdx.x * 256 + wave * 64;   // first element of this wave

    // ---- Phase 1: one-probe lookup (fallback: binary search) ----
    int my_id = 0;
    {
        const int e = wbase + lane;
        if (e < n_elem) {
            const int u  = x[e];
            const int v1 = userlist[1];                // wave-uniform, L1-hit
            int g = 1 + (u - v1);
            bool hit = false;
            if (g >= 1 && g < n_user) {
                hit = (userlist[g] == u);              // strictly sorted => unique
            }
            if (!hit) {
                int lo = 0, hi = n_user;               // lower_bound fallback
                while (lo < hi) {
                    const int mid = (lo + hi) >> 1;
                    if (userlist[mid] < u) lo = mid + 1;
                    else                   hi = mid;
                }
                g = lo;
            }
            my_id = g;
        }
    }

    // ---- Phase 2: wave-local gather of 64 rows ----
    const f32x4* __restrict__ emb4 = (const f32x4*)emb;
    f32x4*       __restrict__ out4 = (f32x4*)out;

    const int sub   = lane & (V4_PER_ROW - 1);  // float4 index within row
    const int eslot = lane >> 4;                // 0..3

#pragma unroll
    for (int iter = 0; iter < 16; ++iter) {
        const int local = eslot + iter * 4;     // 0..63
        const int id    = __shfl(my_id, local); // id from owner lane
        const int ge    = wbase + local;
        if (ge < n_elem) {
            const f32x4 row = emb4[(size_t)id * V4_PER_ROW + sub];
            store_nt_f4(&out4[(size_t)ge * V4_PER_ROW + sub], row);
        }
    }
}

extern "C" void kernel_launch(void* const* d_in, const int* in_sizes, int n_in,
                              void* d_out, int out_size, void* d_ws, size_t ws_size,
                              hipStream_t stream) {
    const int*   x        = (const int*)d_in[0];    // [BATCH*HIST] indices
    const int*   userlist = (const int*)d_in[1];    // [USR_SIZE+1] sorted ids
    const float* emb      = (const float*)d_in[2];  // [USR_SIZE+1, 64]
    float*       out      = (float*)d_out;          // [BATCH*HIST, 64]

    const int n_elem = in_sizes[0];                 // 819200
    const int n_user = in_sizes[1];                 // 100001

    const int blocks = (n_elem + 255) / 256;        // 3200
    usr_emb_gather<<<blocks, 256, 0, stream>>>(x, userlist, n_user, emb, out, n_elem);
}